// Round 6
// baseline (330.983 us; speedup 1.0000x reference)
//
#include <hip/hip_runtime.h>
#include <cstdint>
#include <cstddef>

// Model dims
#define Hn 100      // hidden
#define Tn 25       // timesteps
#define Bn 512      // batch
#define FCn 128
#define Rr 2        // rows (batch elems) per block
#define NBLK (Bn / Rr)   // 256 blocks -> all 256 CUs
#define NTHR 1024        // 16 waves

// MFMA structure: z[400] per layer = 25 col-tiles of 16 (o = 4u+g order).
// Wave w (w7 = w&7 < 7, wl = w>>3): layer wl, tiles ct = w7 + 7t, t=0..3
// (t=3 valid iff w7<4): 7 waves x {4,4,4,4,3,3,3} = 25 tiles per layer.
// Waves 7,15: x(t+1) embedding prefetch only.
// A-residency: t0 all waves + t1 of w7<4 in LDS (22 slots, 140.8 KB);
// every work wave streams exactly 2 tiles from L2 (balanced).
// D-layout (HW-verified): col=lane&15 (batch slot j), row=(lane>>4)*4+reg
// = z-col in tile -> lane 16q+j holds unit u=4ct+q, row j, gates i,j,f,o
// in acc[0..3]: cell update is lane-local, no shuffles, no redundancy.

typedef _Float16 half2_t __attribute__((ext_vector_type(2)));
typedef _Float16 f16x8  __attribute__((ext_vector_type(8)));
typedef float    f32x4  __attribute__((ext_vector_type(4)));

__device__ __forceinline__ f16x8 asf16(uint4 v) {
    union { uint4 u; f16x8 h; } x; x.u = v; return x.h;
}
__device__ __forceinline__ float sigm(float x) {
    return __fdividef(1.0f, 1.0f + __expf(-x));
}
__device__ __forceinline__ float tanh_fast(float x) {
    float e = __expf(2.0f * x);
    return __fdividef(e - 1.0f, e + 1.0f);
}

// ---------------------------------------------------------------------------
// Prep: repack k1,k2 (fp32 [200][400], columns c = g*100+u, gates i,j,f,o)
// into fp16 chunk layout WP[l][kq][o] (uint4), o = 4u+g owning column c.
// Chunk kq covers k = 8kq..8kq+7 (dword j = pair k=8kq+2j, 8kq+2j+1).
// This doubles as the MFMA A-fragment layout: lane l of tile ct reads
// col o = 16ct + (l&15), k-chunk kq = 4s + (l>>4) for k-step s.
// ---------------------------------------------------------------------------
__global__ void prep_weights(const float* __restrict__ k1,
                             const float* __restrict__ k2,
                             uint4* __restrict__ WP) {
    int t = blockIdx.x * blockDim.x + threadIdx.x;
    if (t >= 2 * 25 * 400) return;
    int l   = t / 10000;
    int rem = t % 10000;
    int kq  = rem / 400;
    int o   = rem % 400;
    int u = o >> 2, g = o & 3;
    int c = g * 100 + u;
    const float* K = l ? k2 : k1;
    union { unsigned u32; half2_t h; } d[4];
    #pragma unroll
    for (int jj = 0; jj < 4; jj++) {
        int k0 = 8 * kq + 2 * jj;
        d[jj].h.x = (_Float16)K[(k0    ) * 400 + c];
        d[jj].h.y = (_Float16)K[(k0 + 1) * 400 + c];
    }
    uint4 v; v.x = d[0].u32; v.y = d[1].u32; v.z = d[2].u32; v.w = d[3].u32;
    WP[t] = v;
}

__global__ __launch_bounds__(NTHR, 1) void lstm_main(
    const int*   __restrict__ features,   // [B][T]
    const float* __restrict__ embedding,  // [VOCAB][H]
    const float* __restrict__ b1,         // [400]
    const float* __restrict__ b2,         // [400]
    const float* __restrict__ w_fc1,      // [100][128]
    const float* __restrict__ b_fc1,      // [128]
    const float* __restrict__ w_fc2,      // [128][2]
    const float* __restrict__ b_fc2,      // [2]
    const uint4* __restrict__ WP,         // [2][25][400] fp16 chunks
    float*       __restrict__ out)        // [B][2]
{
    // 140,800 + 1,600 + 1,600 + 400 + 3,200 + 64 = 147,664 B (< R5's 150.5K)
    __shared__ __align__(16) uint4    WLA[22 * 400];    // A-tile cache
    __shared__ __align__(16) _Float16 xh1[2][Rr][200];  // [x(100) | h1(100)]
    __shared__ __align__(16) _Float16 xh2[2][Rr][200];  // [h1(100) | h2(100)]
    __shared__ __align__(16) uint4    zrow[25];         // zero B-row (j>=2)
    __shared__ __align__(16) float    bias_lds[800];    // [l][u][g] packed
    __shared__ float wred[8][2];

    const int tid  = threadIdx.x;
    const int lane = tid & 63;
    const int w    = tid >> 6;          // wave 0..15
    const int wl   = w >> 3;            // layer of this wave group
    const int w7   = w & 7;
    const bool workw = (w7 < 7);        // waves 7,15 = prefetch-only
    const int q = lane >> 4;            // 0..3 (k-chunk group / unit-in-tile)
    const int j = lane & 15;            // batch slot (0,1 real)

    // ---- one-time staging ----
    // WLA slots: s<14: (l=s/7, ct=s%7, t=0); s>=14: e=s-14 -> (l=e>>2, ct=(e&3)+7)
    for (int idx = tid; idx < 22 * 400; idx += NTHR) {
        int s   = idx / 400;
        int rem = idx - s * 400;
        int kq  = rem >> 4;
        int c16 = rem & 15;
        int l_t, ct;
        if (s < 14) { l_t = s / 7; ct = s - l_t * 7; }
        else        { int e = s - 14; l_t = e >> 2; ct = (e & 3) + 7; }
        WLA[idx] = WP[(l_t * 25 + kq) * 400 + 16 * ct + c16];
    }
    if (tid < 800) {                    // bias_lds[l*400 + u*4 + g]
        int l_b  = tid / 400;
        int rest = tid - l_b * 400;
        int u = rest >> 2, g = rest & 3;
        bias_lds[tid] = (l_b ? b2 : b1)[g * 100 + u];
    }
    if (tid < 25) { uint4 z; z.x = z.y = z.z = z.w = 0u; zrow[tid] = z; }
    if (tid < 200) {
        int r = tid / 100, uu = tid % 100;
        xh1[0][r][100 + uu] = (_Float16)0.f;
        xh2[1][r][100 + uu] = (_Float16)0.f;
    }
    if (tid < 100) {                    // stage x(0)
        int r = tid / 50, pp = tid % 50;
        int f0 = features[(blockIdx.x * Rr + r) * Tn];
        float2 e = *(const float2*)(embedding + (size_t)f0 * Hn + 2 * pp);
        half2_t h; h.x = (_Float16)e.x; h.y = (_Float16)e.y;
        ((half2_t*)&xh1[0][r][0])[pp] = h;
    }
    __syncthreads();

    // ---- per-wave constants ----
    const int ct0 = w7;                  // tiles (work waves): always valid
    const int ct1 = w7 + 7;
    const int ct2 = w7 + 14;
    const int ct3 = w7 + 21;
    const bool v3   = workw && (ct3 < 25);     // t=3 valid iff w7<4
    const int slot0 = w7 + 7 * wl;             // LDS slot, t=0
    const bool t1lds = (w7 < 4);
    const int slot1 = 14 + w7 + 4 * wl;        // LDS slot, t=1 (w7<4)
    // global A base: + kq*400 walks k-chunks; +112/224/336 selects t=1/2/3
    const uint4* gA = WP + (size_t)(wl * 25) * 400 + 16 * w7 + j;
    const int bb = wl * 100;                   // bias_lds layer base (units)

    float cst0 = 0.f, cst1 = 0.f, cst2 = 0.f, cst3 = 0.f;

#define CELL(ACC, CST, CT)                                                   \
    {                                                                        \
        float gi = ACC[0], gj = ACC[1], gf = ACC[2], go = ACC[3];            \
        CST = CST * sigm(gf + 1.0f) + sigm(gi) * tanh_fast(gj);              \
        float hh = tanh_fast(CST) * sigm(go);                                \
        if (j < 2) {                                                         \
            _Float16 h16 = (_Float16)hh;                                     \
            int u = 4 * (CT) + q;                                            \
            if (wl == 0) { xh1[wb][j][100 + u] = h16;                        \
                           xh2[wb][j][u]       = h16; }                      \
            else           xh2[wb][j][100 + u] = h16;                        \
        }                                                                    \
    }

    #pragma unroll 1
    for (int ph = 0; ph <= Tn; ph++) {
        const int p  = ph & 1;               // read buffer
        const int wb = p ^ 1;                // write buffer
        if (workw) {
            // layer-1 waves: phases 0..24 (h1(ph)); layer-2: 1..25 (h2(ph-1))
            const bool dorun = wl ? (ph >= 1) : (ph < Tn);
            if (dorun) {
                const uint4* bbase = wl ? (const uint4*)&xh2[p][0][0]
                                        : (const uint4*)&xh1[p][0][0];
                const uint4* brow = (j < 2) ? (bbase + j * 25) : zrow;

                f32x4 acc0 = *(const f32x4*)&bias_lds[(bb + 4 * ct0 + q) * 4];
                f32x4 acc1 = *(const f32x4*)&bias_lds[(bb + 4 * ct1 + q) * 4];
                f32x4 acc2 = *(const f32x4*)&bias_lds[(bb + 4 * ct2 + q) * 4];
                f32x4 acc3;
                if (v3) acc3 = *(const f32x4*)&bias_lds[(bb + 4 * ct3 + q) * 4];
                else    { acc3[0]=0.f; acc3[1]=0.f; acc3[2]=0.f; acc3[3]=0.f; }

                #pragma unroll
                for (int s = 0; s < 7; s++) {
                    const int kq = (s < 6) ? (4 * s + q) : 24;   // K=200 tail
                    f16x8 bf;
                    if (s < 6) bf = asf16(brow[kq]);
                    else {     // only k-group q==0 carries k=192..199
                        const uint4* b6 = (q == 0) ? brow : zrow;
                        bf = asf16(b6[24]);
                    }
                    f16x8 a0 = asf16(WLA[slot0 * 400 + kq * 16 + j]);
                    acc0 = __builtin_amdgcn_mfma_f32_16x16x32_f16(a0, bf, acc0, 0, 0, 0);
                    f16x8 a1;
                    if (t1lds) a1 = asf16(WLA[slot1 * 400 + kq * 16 + j]);
                    else       a1 = asf16(gA[kq * 400 + 112]);
                    acc1 = __builtin_amdgcn_mfma_f32_16x16x32_f16(a1, bf, acc1, 0, 0, 0);
                    f16x8 a2 = asf16(gA[kq * 400 + 224]);
                    acc2 = __builtin_amdgcn_mfma_f32_16x16x32_f16(a2, bf, acc2, 0, 0, 0);
                    if (v3) {
                        f16x8 a3 = asf16(gA[kq * 400 + 336]);
                        acc3 = __builtin_amdgcn_mfma_f32_16x16x32_f16(a3, bf, acc3, 0, 0, 0);
                    }
                }
                CELL(acc0, cst0, ct0);
                CELL(acc1, cst1, ct1);
                CELL(acc2, cst2, ct2);
                if (v3) CELL(acc3, cst3, ct3);
            }
        } else {
            // prefetch waves (7,15): stage x(ph+1) into xh1[wb]
            int pid = lane + (wl << 6);          // 0..127
            if (pid < 100 && ph + 1 < Tn) {
                int r = pid / 50, pp = pid % 50;
                int f1 = features[(blockIdx.x * Rr + r) * Tn + ph + 1];
                float2 e = *(const float2*)(embedding + (size_t)f1 * Hn + 2 * pp);
                half2_t hv; hv.x = (_Float16)e.x; hv.y = (_Float16)e.y;
                ((half2_t*)&xh1[wb][r][0])[pp] = hv;
            }
        }
        __syncthreads();                         // publishes visible
    }
    // ph=25 wrote h2(24) into xh2[0]; final barrier made it visible.

    // FC head: pred = (h2 @ w_fc1 + b_fc1) @ w_fc2 + b_fc2
    if (tid < Rr * FCn) {                        // 256 threads: (r,jj)
        int r  = tid >> 7;
        int jj = tid & 127;
        float acc = b_fc1[jj];
        #pragma unroll 10
        for (int uu = 0; uu < Hn; uu++)
            acc = fmaf((float)xh2[0][r][100 + uu], w_fc1[uu * FCn + jj], acc);
        float p0 = acc * w_fc2[2 * jj + 0];
        float p1 = acc * w_fc2[2 * jj + 1];
        #pragma unroll
        for (int off = 32; off > 0; off >>= 1) {
            p0 += __shfl_down(p0, off, 64);
            p1 += __shfl_down(p1, off, 64);
        }
        if (lane == 0) {
            int wv = tid >> 6;
            wred[wv][0] = p0;
            wred[wv][1] = p1;
        }
    }
    __syncthreads();
    if (tid < 4) {
        int r = tid >> 1, cls = tid & 1;
        out[(blockIdx.x * Rr + r) * 2 + cls] =
            wred[2 * r][cls] + wred[2 * r + 1][cls] + b_fc2[cls];
    }
#undef CELL
}

extern "C" void kernel_launch(void* const* d_in, const int* in_sizes, int n_in,
                              void* d_out, int out_size, void* d_ws, size_t ws_size,
                              hipStream_t stream) {
    const int*   features  = (const int*)  d_in[0];
    const float* embedding = (const float*)d_in[1];
    const float* k1        = (const float*)d_in[2];
    const float* b1        = (const float*)d_in[3];
    const float* k2        = (const float*)d_in[4];
    const float* b2        = (const float*)d_in[5];
    const float* w_fc1     = (const float*)d_in[6];
    const float* b_fc1     = (const float*)d_in[7];
    const float* w_fc2     = (const float*)d_in[8];
    const float* b_fc2     = (const float*)d_in[9];

    uint4* WP = (uint4*)d_ws;                 // 2*25*400*16 = 320,000 B

    prep_weights<<<(20000 + 255) / 256, 256, 0, stream>>>(k1, k2, WP);
    lstm_main<<<NBLK, NTHR, 0, stream>>>(features, embedding, b1, b2,
                                         w_fc1, b_fc1, w_fc2, b_fc2,
                                         WP, (float*)d_out);
}

// Round 7
// 327.437 us; speedup vs baseline: 1.0108x; 1.0108x over previous
//
#include <hip/hip_runtime.h>
#include <cstdint>
#include <cstddef>

// Model dims
#define Hn 100      // hidden
#define Tn 25       // timesteps
#define Bn 512      // batch
#define FCn 128
#define Rr 2        // rows (batch elems) per block
#define NBLK (Bn / Rr)   // 256 blocks -> all 256 CUs
#define NTHR 1024        // 16 waves

// MFMA structure (identical math to R6, addressing flattened):
// z[400] per layer = 25 col-tiles of 16 (o = 4u+g order).
// Wave w (w7 = w&7 < 7, wl = w>>3): layer wl, tiles ct = w7 + 7t, t=0..3
// (t=3 valid iff w7<4).  Waves 7,15: x(t+1) embedding prefetch only.
// A-residency: 22 tiles in LDS (t0 all waves + t1 of w7<4), 2 tiles/wave
// streamed from L2.  D-layout: col=lane&15 (batch slot j), row q=(lane>>4)
// -> lane 16q+j holds unit u=4ct+q, row j, gates i,j,f,o in acc[0..3].
//
// R7 change: phase loop unrolled x2 so buffer parity P/WB are compile-time;
// all LDS accesses are [precomputed per-lane base] + [immediate offset]
// (xh parity stride 800B, s-step stride 1024B, all < imm16).  R6 spent
// ~600 VALU instrs/wave/phase on rematerialized addressing (VALUBusy 41%
// at 136us with only ~28 MFMA of work); this removes it at the source.

typedef _Float16 half2_t __attribute__((ext_vector_type(2)));
typedef _Float16 f16x8  __attribute__((ext_vector_type(8)));
typedef float    f32x4  __attribute__((ext_vector_type(4)));

__device__ __forceinline__ f16x8 asf16(uint4 v) {
    union { uint4 u; f16x8 h; } x; x.u = v; return x.h;
}
__device__ __forceinline__ float sigm(float x) {
    return __fdividef(1.0f, 1.0f + __expf(-x));
}
__device__ __forceinline__ float tanh_fast(float x) {
    float e = __expf(2.0f * x);
    return __fdividef(e - 1.0f, e + 1.0f);
}
#define MFMA16(A, B, C) __builtin_amdgcn_mfma_f32_16x16x32_f16((A), (B), (C), 0, 0, 0)

// ---------------------------------------------------------------------------
// Prep: repack k1,k2 (fp32 [200][400], columns c = g*100+u, gates i,j,f,o)
// into fp16 chunk layout WP[l][kq][o] (uint4), o = 4u+g owning column c.
// Chunk kq covers k = 8kq..8kq+7 (dword j = pair k=8kq+2j, 8kq+2j+1).
// Doubles as the MFMA A-fragment layout: lane (16q+j) of tile ct reads
// col o = 16ct+j, k-chunk kq = 4s+q for k-step s.
// ---------------------------------------------------------------------------
__global__ void prep_weights(const float* __restrict__ k1,
                             const float* __restrict__ k2,
                             uint4* __restrict__ WP) {
    int t = blockIdx.x * blockDim.x + threadIdx.x;
    if (t >= 2 * 25 * 400) return;
    int l   = t / 10000;
    int rem = t % 10000;
    int kq  = rem / 400;
    int o   = rem % 400;
    int u = o >> 2, g = o & 3;
    int c = g * 100 + u;
    const float* K = l ? k2 : k1;
    union { unsigned u32; half2_t h; } d[4];
    #pragma unroll
    for (int jj = 0; jj < 4; jj++) {
        int k0 = 8 * kq + 2 * jj;
        d[jj].h.x = (_Float16)K[(k0    ) * 400 + c];
        d[jj].h.y = (_Float16)K[(k0 + 1) * 400 + c];
    }
    uint4 v; v.x = d[0].u32; v.y = d[1].u32; v.z = d[2].u32; v.w = d[3].u32;
    WP[t] = v;
}

__global__ __launch_bounds__(NTHR, 1) void lstm_main(
    const int*   __restrict__ features,   // [B][T]
    const float* __restrict__ embedding,  // [VOCAB][H]
    const float* __restrict__ b1,         // [400]
    const float* __restrict__ b2,         // [400]
    const float* __restrict__ w_fc1,      // [100][128]
    const float* __restrict__ b_fc1,      // [128]
    const float* __restrict__ w_fc2,      // [128][2]
    const float* __restrict__ b_fc2,      // [2]
    const uint4* __restrict__ WP,         // [2][25][400] fp16 chunks
    float*       __restrict__ out)        // [B][2]
{
    // 140,800 + 1,600 + 1,600 + 1,600 + 3,200 + 64 = 148,864 B (< 160 KiB)
    __shared__ __align__(16) uint4    WLA[22 * 400];    // A-tile cache
    __shared__ __align__(16) _Float16 xh1[2][Rr][200];  // [x(100) | h1(100)]
    __shared__ __align__(16) _Float16 xh2[2][Rr][200];  // [h1(100) | h2(100)]
    __shared__ __align__(16) _Float16 zpad[2][Rr][200]; // zeros, xh-shaped
    __shared__ __align__(16) float    bias_lds[800];    // [l][u][g] packed
    __shared__ float wred[8][2];

    const int tid  = threadIdx.x;
    const int lane = tid & 63;
    const int w    = tid >> 6;          // wave 0..15
    const int wl   = w >> 3;            // layer of this wave group
    const int w7   = w & 7;
    const bool workw = (w7 < 7);        // waves 7,15 = prefetch-only
    const int q = lane >> 4;            // 0..3 (k-chunk group / unit-in-tile)
    const int j = lane & 15;            // batch slot (0,1 real)

    // ---- one-time staging ----
    for (int idx = tid; idx < 22 * 400; idx += NTHR) {
        int s   = idx / 400;
        int rem = idx - s * 400;
        int kq  = rem >> 4;
        int c16 = rem & 15;
        int l_t, ct;
        if (s < 14) { l_t = s / 7; ct = s - l_t * 7; }
        else        { int e = s - 14; l_t = e >> 2; ct = (e & 3) + 7; }
        WLA[idx] = WP[(l_t * 25 + kq) * 400 + 16 * ct + c16];
    }
    if (tid < 800) {                    // bias_lds[l*400 + u*4 + g]
        int l_b  = tid / 400;
        int rest = tid - l_b * 400;
        int u = rest >> 2, g = rest & 3;
        bias_lds[tid] = (l_b ? b2 : b1)[g * 100 + u];
    }
    if (tid < 100) ((uint4*)zpad)[tid] = (uint4){0u, 0u, 0u, 0u};
    if (tid < 200) {
        int r = tid / 100, uu = tid % 100;
        xh1[0][r][100 + uu] = (_Float16)0.f;
        xh2[1][r][100 + uu] = (_Float16)0.f;
    }
    if (tid < 100) {                    // stage x(0)
        int r = tid / 50, pp = tid % 50;
        int f0 = features[(blockIdx.x * Rr + r) * Tn];
        float2 e = *(const float2*)(embedding + (size_t)f0 * Hn + 2 * pp);
        half2_t h; h.x = (_Float16)e.x; h.y = (_Float16)e.y;
        ((half2_t*)&xh1[0][r][0])[pp] = h;
    }
    __syncthreads();

    // ---- per-wave / per-lane constants and base pointers ----
    const int ct0 = w7;
    const bool v3    = workw && (w7 < 4);      // t=3 tile exists
    const bool t1lds = (w7 < 4);               // t=1 tile cached in LDS
    const int slot0  = w7 + 7 * wl;
    const int slot1c = t1lds ? (14 + w7 + 4 * wl) : 0;   // clamped (spec-safe)

    const _Float16* xh_rd = wl ? &xh2[0][0][0] : &xh1[0][0][0];
    // B-fragment bases (per-lane; parity/s-step become immediates):
    //   read at [P*50 + 4s] (uint4 units): byte = P*800 + s*64 (+16q in base)
    const uint4* browp  = (j < 2) ? ((const uint4*)(xh_rd + j * 200) + q)
                                  : ((const uint4*)zpad + q);
    const uint4* brow6p = (q == 0 && j < 2) ? (const uint4*)(xh_rd + j * 200)
                                            : (const uint4*)zpad;
    // A-fragment LDS bases: read at [64s]; tails (kq=24, q-free) at [384].
    const uint4* wla0p = WLA + slot0  * 400 + 16 * q + j;
    const uint4* wt0p  = WLA + slot0  * 400 + j;
    const uint4* wla1p = WLA + slot1c * 400 + 16 * q + j;
    const uint4* wt1p  = WLA + slot1c * 400 + j;
    // streamed A base (global, L2-resident)
    const uint4* gAp = WP + (size_t)(wl * 25) * 400 + 16 * w7 + j;
    // bias base (f32x4 units): acc_t = biasp[28*t]
    const f32x4* biasp = (const f32x4*)&bias_lds[(wl * 100 + 4 * ct0 + q) * 4];
    // store bases (_Float16 units): elem = [WB*400 + j*200 + (off) + 4ct + q]
    _Float16* h1st = &xh1[0][0][0] + j * 200 + 100 + q;  // h1 recurrent
    _Float16* h2in = &xh2[0][0][0] + j * 200 + q;        // h1 -> layer2 input
    _Float16* h2st = &xh2[0][0][0] + j * 200 + 100 + q;  // h2 out

    float cst0 = 0.f, cst1 = 0.f, cst2 = 0.f, cst3 = 0.f;

#define CELL(ACC, CST, CT, WB)                                               \
    {                                                                        \
        float gi = ACC[0], gj = ACC[1], gf = ACC[2], go = ACC[3];            \
        CST = CST * sigm(gf + 1.0f) + sigm(gi) * tanh_fast(gj);              \
        float hh = tanh_fast(CST) * sigm(go);                                \
        if (j < 2) {                                                         \
            _Float16 h16 = (_Float16)hh;                                     \
            if (wl == 0) { h1st[(WB) * 400 + 4 * (CT)] = h16;                \
                           h2in[(WB) * 400 + 4 * (CT)] = h16; }              \
            else           h2st[(WB) * 400 + 4 * (CT)] = h16;                \
        }                                                                    \
    }

#define SSTEP(S, P)                                                          \
    {                                                                        \
        f16x8 bf = asf16(browp[(P) * 50 + 4 * (S)]);                         \
        f16x8 a0 = asf16(wla0p[64 * (S)]);                                   \
        acc0 = MFMA16(a0, bf, acc0);                                         \
        f16x8 a1 = t1lds ? asf16(wla1p[64 * (S)])                            \
                         : asf16(gAp[(4 * (S) + q) * 400 + 112]);            \
        acc1 = MFMA16(a1, bf, acc1);                                         \
        f16x8 a2 = asf16(gAp[(4 * (S) + q) * 400 + 224]);                    \
        acc2 = MFMA16(a2, bf, acc2);                                         \
        if (v3) {                                                            \
            f16x8 a3 = asf16(gAp[(4 * (S) + q) * 400 + 336]);                \
            acc3 = MFMA16(a3, bf, acc3);                                     \
        }                                                                    \
    }

#define PHASE(PH, P, WB)                                                     \
    {                                                                        \
        if (workw) {                                                         \
            if (wl ? ((PH) >= 1) : ((PH) < Tn)) {                            \
                f32x4 acc0 = biasp[0];                                       \
                f32x4 acc1 = biasp[28];                                      \
                f32x4 acc2 = biasp[56];                                      \
                f32x4 acc3;                                                  \
                if (v3) acc3 = biasp[84];                                    \
                else { acc3[0]=0.f; acc3[1]=0.f; acc3[2]=0.f; acc3[3]=0.f; } \
                SSTEP(0, P) SSTEP(1, P) SSTEP(2, P)                          \
                SSTEP(3, P) SSTEP(4, P) SSTEP(5, P)                          \
                { /* tail: kq=24 carries k=192..199 only in q-group 0 */     \
                    f16x8 bf6 = asf16(brow6p[(P) * 50 + 24]);                \
                    f16x8 a0t = asf16(wt0p[384]);                            \
                    acc0 = MFMA16(a0t, bf6, acc0);                           \
                    f16x8 a1t = t1lds ? asf16(wt1p[384])                     \
                                      : asf16(gAp[24 * 400 + 112]);          \
                    acc1 = MFMA16(a1t, bf6, acc1);                           \
                    f16x8 a2t = asf16(gAp[24 * 400 + 224]);                  \
                    acc2 = MFMA16(a2t, bf6, acc2);                           \
                    if (v3) {                                                \
                        f16x8 a3t = asf16(gAp[24 * 400 + 336]);              \
                        acc3 = MFMA16(a3t, bf6, acc3);                       \
                    }                                                        \
                }                                                            \
                CELL(acc0, cst0, ct0,      WB)                               \
                CELL(acc1, cst1, ct0 + 7,  WB)                               \
                CELL(acc2, cst2, ct0 + 14, WB)                               \
                if (v3) CELL(acc3, cst3, ct0 + 21, WB)                       \
            }                                                                \
        } else {                                                             \
            int pid = lane + (wl << 6);                                      \
            if (pid < 100 && (PH) + 1 < Tn) {                                \
                int r = pid / 50, pp = pid % 50;                             \
                int f1 = features[(blockIdx.x * Rr + r) * Tn + (PH) + 1];    \
                float2 e = *(const float2*)(embedding                        \
                                            + (size_t)f1 * Hn + 2 * pp);     \
                half2_t hv; hv.x = (_Float16)e.x; hv.y = (_Float16)e.y;      \
                ((half2_t*)&xh1[WB][r][0])[pp] = hv;                         \
            }                                                                \
        }                                                                    \
        __syncthreads();                                                     \
    }

    for (int ph = 0; ph < 26; ph += 2) {
        PHASE(ph,     0, 1)
        PHASE(ph + 1, 1, 0)
    }
    // ph=25 wrote h2(24) into xh2[0]; its trailing barrier made it visible.

    // FC head: pred = (h2 @ w_fc1 + b_fc1) @ w_fc2 + b_fc2
    if (tid < Rr * FCn) {                        // 256 threads: (r,jj)
        int r  = tid >> 7;
        int jj = tid & 127;
        float acc = b_fc1[jj];
        #pragma unroll 10
        for (int uu = 0; uu < Hn; uu++)
            acc = fmaf((float)xh2[0][r][100 + uu], w_fc1[uu * FCn + jj], acc);
        float p0 = acc * w_fc2[2 * jj + 0];
        float p1 = acc * w_fc2[2 * jj + 1];
        #pragma unroll
        for (int off = 32; off > 0; off >>= 1) {
            p0 += __shfl_down(p0, off, 64);
            p1 += __shfl_down(p1, off, 64);
        }
        if (lane == 0) {
            int wv = tid >> 6;
            wred[wv][0] = p0;
            wred[wv][1] = p1;
        }
    }
    __syncthreads();
    if (tid < 4) {
        int r = tid >> 1, cls = tid & 1;
        out[(blockIdx.x * Rr + r) * 2 + cls] =
            wred[2 * r][cls] + wred[2 * r + 1][cls] + b_fc2[cls];
    }
#undef PHASE
#undef SSTEP
#undef CELL
}

extern "C" void kernel_launch(void* const* d_in, const int* in_sizes, int n_in,
                              void* d_out, int out_size, void* d_ws, size_t ws_size,
                              hipStream_t stream) {
    const int*   features  = (const int*)  d_in[0];
    const float* embedding = (const float*)d_in[1];
    const float* k1        = (const float*)d_in[2];
    const float* b1        = (const float*)d_in[3];
    const float* k2        = (const float*)d_in[4];
    const float* b2        = (const float*)d_in[5];
    const float* w_fc1     = (const float*)d_in[6];
    const float* b_fc1     = (const float*)d_in[7];
    const float* w_fc2     = (const float*)d_in[8];
    const float* b_fc2     = (const float*)d_in[9];

    uint4* WP = (uint4*)d_ws;                 // 2*25*400*16 = 320,000 B

    prep_weights<<<(20000 + 255) / 256, 256, 0, stream>>>(k1, k2, WP);
    lstm_main<<<NBLK, NTHR, 0, stream>>>(features, embedding, b1, b2,
                                         w_fc1, b_fc1, w_fc2, b_fc2,
                                         WP, (float*)d_out);
}

// Round 8
// 327.189 us; speedup vs baseline: 1.0116x; 1.0008x over previous
//
#include <hip/hip_runtime.h>
#include <cstdint>
#include <cstddef>

// Model dims
#define Hn 100      // hidden
#define Tn 25       // timesteps
#define Bn 512      // batch
#define FCn 128
#define Rr 2        // rows (batch elems) per block
#define NBLK (Bn / Rr)   // 256 blocks -> all 256 CUs
#define NTHR 1024        // 16 waves

// MFMA structure (identical math to R7):
// z[400] per layer = 25 col-tiles of 16 (o = 4u+g order).
// Wave w (w7 = w&7 < 7, wl = w>>3): layer wl, tiles ct = w7 + 7t, t=0..3
// (t=3 valid iff w7<4).  Waves 7,15: per-phase x(t+1) LDS->LDS copy.
// A-residency: 20 tiles in LDS (t0 all waves + t1 of w7<3); w7<3 streams
// t2,t3; w7==3 streams t1,t2,t3; w7 4-6 streams t1,t2 (L2-resident WP).
// D-layout: col=lane&15 (batch slot j), row q=(lane>>4) -> lane 16q+j holds
// unit u=4ct+q, row j, gates i,j,f,o in acc[0..3]: lane-local cell update.
//
// R8 change (phase-latency theory): ALL embedding gathers hoisted to init.
// R0-R7 all ran a dependent global chain (features idx -> HBM-random
// embedding row) inside every phase's barrier set; with vmcnt(0) drained
// before s_barrier, that ~1-4K-cycle chain was on every phase's critical
// path.  x(t) depends only on features -> stage xemb[25][2][100] once;
// per-phase copy is 2 LDS instrs by waves 7/15.

typedef _Float16 half2_t __attribute__((ext_vector_type(2)));
typedef _Float16 f16x8  __attribute__((ext_vector_type(8)));
typedef float    f32x4  __attribute__((ext_vector_type(4)));

__device__ __forceinline__ f16x8 asf16(uint4 v) {
    union { uint4 u; f16x8 h; } x; x.u = v; return x.h;
}
__device__ __forceinline__ float sigm(float x) {
    return __fdividef(1.0f, 1.0f + __expf(-x));
}
__device__ __forceinline__ float tanh_fast(float x) {
    float e = __expf(2.0f * x);
    return __fdividef(e - 1.0f, e + 1.0f);
}
#define MFMA16(A, B, C) __builtin_amdgcn_mfma_f32_16x16x32_f16((A), (B), (C), 0, 0, 0)

// ---------------------------------------------------------------------------
// Prep: repack k1,k2 (fp32 [200][400], columns c = g*100+u, gates i,j,f,o)
// into fp16 chunk layout WP[l][kq][o] (uint4), o = 4u+g owning column c.
// Chunk kq covers k = 8kq..8kq+7 (dword j = pair k=8kq+2j, 8kq+2j+1).
// Doubles as the MFMA A-fragment layout: lane (16q+j) of tile ct reads
// col o = 16ct+j, k-chunk kq = 4s+q for k-step s.
// ---------------------------------------------------------------------------
__global__ void prep_weights(const float* __restrict__ k1,
                             const float* __restrict__ k2,
                             uint4* __restrict__ WP) {
    int t = blockIdx.x * blockDim.x + threadIdx.x;
    if (t >= 2 * 25 * 400) return;
    int l   = t / 10000;
    int rem = t % 10000;
    int kq  = rem / 400;
    int o   = rem % 400;
    int u = o >> 2, g = o & 3;
    int c = g * 100 + u;
    const float* K = l ? k2 : k1;
    union { unsigned u32; half2_t h; } d[4];
    #pragma unroll
    for (int jj = 0; jj < 4; jj++) {
        int k0 = 8 * kq + 2 * jj;
        d[jj].h.x = (_Float16)K[(k0    ) * 400 + c];
        d[jj].h.y = (_Float16)K[(k0 + 1) * 400 + c];
    }
    uint4 v; v.x = d[0].u32; v.y = d[1].u32; v.z = d[2].u32; v.w = d[3].u32;
    WP[t] = v;
}

__global__ __launch_bounds__(NTHR, 1) void lstm_main(
    const int*   __restrict__ features,   // [B][T]
    const float* __restrict__ embedding,  // [VOCAB][H]
    const float* __restrict__ b1,         // [400]
    const float* __restrict__ b2,         // [400]
    const float* __restrict__ w_fc1,      // [100][128]
    const float* __restrict__ b_fc1,      // [128]
    const float* __restrict__ w_fc2,      // [128][2]
    const float* __restrict__ b_fc2,      // [2]
    const uint4* __restrict__ WP,         // [2][25][400] fp16 chunks
    float*       __restrict__ out)        // [B][2]
{
    // 128,000 + 1,600 + 1,600 + 1,600 + 3,200 + 10,000 + 64 = 146,064 B
    __shared__ __align__(16) uint4    WLA[20 * 400];    // A-tile cache
    __shared__ __align__(16) _Float16 xh1[2][Rr][200];  // [x(100) | h1(100)]
    __shared__ __align__(16) _Float16 xh2[2][Rr][200];  // [h1(100) | h2(100)]
    __shared__ __align__(16) _Float16 zpad[2][Rr][200]; // zeros, xh-shaped
    __shared__ __align__(16) float    bias_lds[800];    // [l][u][g] packed
    __shared__ __align__(16) _Float16 xemb[Tn][Rr][100];// all steps' x
    __shared__ float wred[8][2];

    const int tid  = threadIdx.x;
    const int lane = tid & 63;
    const int w    = tid >> 6;          // wave 0..15
    const int wl   = w >> 3;            // layer of this wave group
    const int w7   = w & 7;
    const bool workw = (w7 < 7);        // waves 7,15 = copier waves
    const int q = lane >> 4;            // 0..3 (k-chunk group / unit-in-tile)
    const int j = lane & 15;            // batch slot (0,1 real)

    // ---- one-time staging ----
    // WLA slots: s<14: (l=s/7, ct=s%7, t=0); s>=14: e=s-14 -> (l=e/3, ct=(e%3)+7)
    for (int idx = tid; idx < 20 * 400; idx += NTHR) {
        int s   = idx / 400;
        int rem = idx - s * 400;
        int kq  = rem >> 4;
        int c16 = rem & 15;
        int l_t, ct;
        if (s < 14) { l_t = s / 7; ct = s - l_t * 7; }
        else        { int e = s - 14; l_t = e / 3; ct = (e % 3) + 7; }
        WLA[idx] = WP[(l_t * 25 + kq) * 400 + 16 * ct + c16];
    }
    // all 25 steps x 2 rows of embeddings -> LDS (one parallel burst)
    for (int i = tid; i < Tn * Rr * 50; i += NTHR) {   // 2500 half2 units
        int t   = i / 100;
        int rem = i - t * 100;
        int r = rem / 50, pp = rem - r * 50;
        int f = features[(blockIdx.x * Rr + r) * Tn + t];
        float2 e = *(const float2*)(embedding + (size_t)f * Hn + 2 * pp);
        half2_t h; h.x = (_Float16)e.x; h.y = (_Float16)e.y;
        ((half2_t*)&xemb[t][r][0])[pp] = h;
    }
    if (tid < 800) {                    // bias_lds[l*400 + u*4 + g]
        int l_b  = tid / 400;
        int rest = tid - l_b * 400;
        int u = rest >> 2, g = rest & 3;
        bias_lds[tid] = (l_b ? b2 : b1)[g * 100 + u];
    }
    if (tid < 100) ((uint4*)zpad)[tid] = (uint4){0u, 0u, 0u, 0u};
    if (tid < 200) {
        int r = tid / 100, uu = tid % 100;
        xh1[0][r][100 + uu] = (_Float16)0.f;
        xh2[1][r][100 + uu] = (_Float16)0.f;
    }
    if (tid < 100) {                    // stage x(0) (embedding re-read: cached)
        int r = tid / 50, pp = tid % 50;
        int f0 = features[(blockIdx.x * Rr + r) * Tn];
        float2 e = *(const float2*)(embedding + (size_t)f0 * Hn + 2 * pp);
        half2_t h; h.x = (_Float16)e.x; h.y = (_Float16)e.y;
        ((half2_t*)&xh1[0][r][0])[pp] = h;
    }
    __syncthreads();

    // ---- per-wave / per-lane constants and base pointers ----
    const int ct0 = w7;
    const bool v3    = workw && (w7 < 4);      // t=3 tile exists
    const bool t1lds = (w7 < 3);               // t=1 tile cached in LDS
    const int slot0  = w7 + 7 * wl;
    const int slot1c = t1lds ? (14 + w7 + 3 * wl) : 0;   // clamped

    const _Float16* xh_rd = wl ? &xh2[0][0][0] : &xh1[0][0][0];
    // B-fragment bases: read at [P*50 + 4s] (uint4): byte = P*800 + s*64
    const uint4* browp  = (j < 2) ? ((const uint4*)(xh_rd + j * 200) + q)
                                  : ((const uint4*)zpad + q);
    const uint4* brow6p = (q == 0 && j < 2) ? (const uint4*)(xh_rd + j * 200)
                                            : (const uint4*)zpad;
    // A-fragment LDS bases: read at [64s]; tails (kq=24, q-free) at [384].
    const uint4* wla0p = WLA + slot0  * 400 + 16 * q + j;
    const uint4* wt0p  = WLA + slot0  * 400 + j;
    const uint4* wla1p = WLA + slot1c * 400 + 16 * q + j;
    const uint4* wt1p  = WLA + slot1c * 400 + j;
    // streamed A base (global, L2-resident)
    const uint4* gAp = WP + (size_t)(wl * 25) * 400 + 16 * w7 + j;
    // bias base (f32x4 units): acc_t = biasp[28*t]
    const f32x4* biasp = (const f32x4*)&bias_lds[(wl * 100 + 4 * ct0 + q) * 4];
    // store bases (_Float16 units)
    _Float16* h1st = &xh1[0][0][0] + j * 200 + 100 + q;  // h1 recurrent
    _Float16* h2in = &xh2[0][0][0] + j * 200 + q;        // h1 -> layer2 input
    _Float16* h2st = &xh2[0][0][0] + j * 200 + 100 + q;  // h2 out
    // copier-wave bases (waves 7/15): x(ph+1) xemb -> xh1[WB]
    const int pid  = lane + (wl << 6);          // 0..127
    const int pidc = (pid < 100) ? pid : 0;
    const int cr = pidc / 50, cp = pidc % 50;
    const unsigned* xe_rd = (const unsigned*)&xemb[0][0][0] + cr * 50 + cp;
    unsigned*       xw_wr = (unsigned*)&xh1[0][0][0] + cr * 100 + cp;

    float cst0 = 0.f, cst1 = 0.f, cst2 = 0.f, cst3 = 0.f;

#define CELL(ACC, CST, CT, WB)                                               \
    {                                                                        \
        float gi = ACC[0], gj = ACC[1], gf = ACC[2], go = ACC[3];            \
        CST = CST * sigm(gf + 1.0f) + sigm(gi) * tanh_fast(gj);              \
        float hh = tanh_fast(CST) * sigm(go);                                \
        if (j < 2) {                                                         \
            _Float16 h16 = (_Float16)hh;                                     \
            if (wl == 0) { h1st[(WB) * 400 + 4 * (CT)] = h16;                \
                           h2in[(WB) * 400 + 4 * (CT)] = h16; }              \
            else           h2st[(WB) * 400 + 4 * (CT)] = h16;                \
        }                                                                    \
    }

#define SSTEP(S, P)                                                          \
    {                                                                        \
        f16x8 bf = asf16(browp[(P) * 50 + 4 * (S)]);                         \
        f16x8 a0 = asf16(wla0p[64 * (S)]);                                   \
        acc0 = MFMA16(a0, bf, acc0);                                         \
        f16x8 a1 = t1lds ? asf16(wla1p[64 * (S)])                            \
                         : asf16(gAp[(4 * (S) + q) * 400 + 112]);            \
        acc1 = MFMA16(a1, bf, acc1);                                         \
        f16x8 a2 = asf16(gAp[(4 * (S) + q) * 400 + 224]);                    \
        acc2 = MFMA16(a2, bf, acc2);                                         \
        if (v3) {                                                            \
            f16x8 a3 = asf16(gAp[(4 * (S) + q) * 400 + 336]);                \
            acc3 = MFMA16(a3, bf, acc3);                                     \
        }                                                                    \
    }

#define PHASE(PH, P, WB)                                                     \
    {                                                                        \
        if (workw) {                                                         \
            if (wl ? ((PH) >= 1) : ((PH) < Tn)) {                            \
                f32x4 acc0 = biasp[0];                                       \
                f32x4 acc1 = biasp[28];                                      \
                f32x4 acc2 = biasp[56];                                      \
                f32x4 acc3;                                                  \
                if (v3) acc3 = biasp[84];                                    \
                else { acc3[0]=0.f; acc3[1]=0.f; acc3[2]=0.f; acc3[3]=0.f; } \
                SSTEP(0, P) SSTEP(1, P) SSTEP(2, P)                          \
                SSTEP(3, P) SSTEP(4, P) SSTEP(5, P)                          \
                { /* tail: kq=24 carries k=192..199 only in q-group 0 */     \
                    f16x8 bf6 = asf16(brow6p[(P) * 50 + 24]);                \
                    f16x8 a0t = asf16(wt0p[384]);                            \
                    acc0 = MFMA16(a0t, bf6, acc0);                           \
                    f16x8 a1t = t1lds ? asf16(wt1p[384])                     \
                                      : asf16(gAp[24 * 400 + 112]);          \
                    acc1 = MFMA16(a1t, bf6, acc1);                           \
                    f16x8 a2t = asf16(gAp[24 * 400 + 224]);                  \
                    acc2 = MFMA16(a2t, bf6, acc2);                           \
                    if (v3) {                                                \
                        f16x8 a3t = asf16(gAp[24 * 400 + 336]);              \
                        acc3 = MFMA16(a3t, bf6, acc3);                       \
                    }                                                        \
                }                                                            \
                CELL(acc0, cst0, ct0,      WB)                               \
                CELL(acc1, cst1, ct0 + 7,  WB)                               \
                CELL(acc2, cst2, ct0 + 14, WB)                               \
                if (v3) CELL(acc3, cst3, ct0 + 21, WB)                       \
            }                                                                \
        } else {                                                             \
            /* copier waves: x(PH+1) LDS->LDS, no global access in loop */   \
            if (pid < 100 && (PH) + 1 < Tn) {                                \
                unsigned v = xe_rd[((PH) + 1) * 100];                        \
                xw_wr[(WB) * 200] = v;                                       \
            }                                                                \
        }                                                                    \
        __syncthreads();                                                     \
    }

    for (int ph = 0; ph < 26; ph += 2) {
        PHASE(ph,     0, 1)
        PHASE(ph + 1, 1, 0)
    }
    // ph=25 wrote h2(24) into xh2[0]; its trailing barrier made it visible.

    // FC head: pred = (h2 @ w_fc1 + b_fc1) @ w_fc2 + b_fc2
    if (tid < Rr * FCn) {                        // 256 threads: (r,jj)
        int r  = tid >> 7;
        int jj = tid & 127;
        float acc = b_fc1[jj];
        #pragma unroll 10
        for (int uu = 0; uu < Hn; uu++)
            acc = fmaf((float)xh2[0][r][100 + uu], w_fc1[uu * FCn + jj], acc);
        float p0 = acc * w_fc2[2 * jj + 0];
        float p1 = acc * w_fc2[2 * jj + 1];
        #pragma unroll
        for (int off = 32; off > 0; off >>= 1) {
            p0 += __shfl_down(p0, off, 64);
            p1 += __shfl_down(p1, off, 64);
        }
        if (lane == 0) {
            int wv = tid >> 6;
            wred[wv][0] = p0;
            wred[wv][1] = p1;
        }
    }
    __syncthreads();
    if (tid < 4) {
        int r = tid >> 1, cls = tid & 1;
        out[(blockIdx.x * Rr + r) * 2 + cls] =
            wred[2 * r][cls] + wred[2 * r + 1][cls] + b_fc2[cls];
    }
#undef PHASE
#undef SSTEP
#undef CELL
}

extern "C" void kernel_launch(void* const* d_in, const int* in_sizes, int n_in,
                              void* d_out, int out_size, void* d_ws, size_t ws_size,
                              hipStream_t stream) {
    const int*   features  = (const int*)  d_in[0];
    const float* embedding = (const float*)d_in[1];
    const float* k1        = (const float*)d_in[2];
    const float* b1        = (const float*)d_in[3];
    const float* k2        = (const float*)d_in[4];
    const float* b2        = (const float*)d_in[5];
    const float* w_fc1     = (const float*)d_in[6];
    const float* b_fc1     = (const float*)d_in[7];
    const float* w_fc2     = (const float*)d_in[8];
    const float* b_fc2     = (const float*)d_in[9];

    uint4* WP = (uint4*)d_ws;                 // 2*25*400*16 = 320,000 B

    prep_weights<<<(20000 + 255) / 256, 256, 0, stream>>>(k1, k2, WP);
    lstm_main<<<NBLK, NTHR, 0, stream>>>(features, embedding, b1, b2,
                                         w_fc1, b_fc1, w_fc2, b_fc2,
                                         WP, (float*)d_out);
}